// Round 2
// baseline (17633.380 us; speedup 1.0000x reference)
//
#include <hip/hip_runtime.h>
#include <hip/hip_cooperative_groups.h>

namespace cg = cooperative_groups;

typedef unsigned short u16;

#define NWG 256
#define NT  256
#define TS  512
#define HD  1024
#define BS  128
#define NI  64
#define NO  64

typedef __attribute__((ext_vector_type(8)))  short bf16x8;
typedef __attribute__((ext_vector_type(16))) float f32x16;

__device__ __forceinline__ float bf2f(u16 u) {
    union { unsigned int i; float f; } v; v.i = ((unsigned int)u) << 16; return v.f;
}
__device__ __forceinline__ u16 f2bf(float f) {
    union { float fl; unsigned int i; } v; v.fl = f;
    unsigned int x = v.i;
    return (u16)((x + 0x7fffu + ((x >> 16) & 1u)) >> 16);  // RNE, finite inputs
}

// Dual-dtype load: the harness's dtype for these inputs is ambiguous from the
// bench output (see round-1 post-mortem); detect at runtime, branch cold paths.
__device__ __forceinline__ float ldv(const void* p, size_t i, bool isf32) {
    return isf32 ? ((const float*)p)[i] : bf2f(((const u16*)p)[i]);
}

// LDS ~91KB -> 1 WG/CU; grid=256 = CU count; cooperative launch guarantees
// co-residency for cg::this_grid().sync().
__global__ __launch_bounds__(NT)
void arnn_persist(const void* __restrict__ xv,
                  const void* __restrict__ encwv,
                  const void* __restrict__ encbv,
                  const void* __restrict__ recwv,
                  const void* __restrict__ fgtwv,
                  const void* __restrict__ decwv,
                  const void* __restrict__ decbv,
                  const void* __restrict__ hinitwv,
                  const void* __restrict__ hinitbv,
                  void* __restrict__ outv,
                  u16* __restrict__ h0buf,
                  u16* __restrict__ h1buf)
{
    // B-fragments pre-swizzled in MFMA lane order: WB[s][lane][8] = W'[lane&31][s*16 + 8*(lane>>5) + i]
    // rows n<16: rec_w[j0+n][k] (k<1024) then enc_w[j0+n][k-1024] (64 cols); rows n>=16: fgt_w, then zeros.
    __shared__ short WB[68 * 64 * 8];      // 69632 B
    __shared__ short DEC[HD];              // 2048 B: dec_w[g][:]
    __shared__ float redC[4][32][33];      // 16896 B (pad 33 breaks bank conflicts)
    __shared__ float hst[32][16];          // fp32 master copy of owned hidden slice
    __shared__ float encbS[16];
    __shared__ float decred[4][32];
    __shared__ float decbS;
    __shared__ int   s_f32;

    cg::grid_group grid = cg::this_grid();

    const int tid  = threadIdx.x;
    const int wg   = blockIdx.x;
    const int q    = wg >> 6;          // batch quarter 0..3
    const int g    = wg & 63;          // column group 0..63 (also the dec output column)
    const int b0   = q * 32;
    const int j0   = g * 16;
    const int wave = tid >> 6;
    const int lane = tid & 63;
    const int arow = lane & 31;        // A-fragment row (batch-local)
    const int khalf = lane >> 5;       // k half within 16-wide MFMA K
    const int s0   = wave * 16;        // K split: wave w handles k-steps [16w, 16w+16)

    // ---- runtime dtype detection on rec_w raw bits ----
    if (tid == 0) s_f32 = 0;
    __syncthreads();
    {
        float v = bf2f(((const u16*)recwv)[tid]);
        if (!(v >= -1.0f && v <= 1.0f)) s_f32 = 1;   // fp32 mantissa halves -> huge/NaN bf16
    }
    __syncthreads();
    const bool isf32 = (s_f32 != 0);

    // ---- init: stage weights into LDS (as bf16) in fragment order ----
    for (int slot = tid; slot < 68 * 64; slot += NT) {
        int s = slot >> 6, l = slot & 63;
        int n = l & 31;
        int kb = s * 16 + 8 * (l >> 5);
        short v[8];
        if (n < 16) {
            int j = j0 + n;
            #pragma unroll
            for (int i = 0; i < 8; ++i) {
                int k = kb + i;
                float w = (k < HD) ? ldv(recwv, (size_t)j * HD + k, isf32)
                                   : ldv(encwv, (size_t)j * NI + (k - HD), isf32);
                v[i] = (short)f2bf(w);
            }
        } else {
            int j = j0 + n - 16;
            #pragma unroll
            for (int i = 0; i < 8; ++i) {
                int k = kb + i;
                v[i] = (k < HD) ? (short)f2bf(ldv(fgtwv, (size_t)j * HD + k, isf32)) : (short)0;
            }
        }
        #pragma unroll
        for (int i = 0; i < 8; ++i) WB[slot * 8 + i] = v[i];
    }
    for (int k = tid; k < HD; k += NT) DEC[k] = (short)f2bf(ldv(decwv, (size_t)g * HD + k, isf32));
    if (tid < 16) encbS[tid] = ldv(encbv, j0 + tid, isf32);
    if (tid == 0) decbS = ldv(decbv, g, isf32);
    // h0 = hinit_w[:,0] + hinit_b (same for every batch row); fp32 local, bf16 global
    for (int e = tid; e < 512; e += NT) {
        int bb = e >> 4, jl = e & 15;
        float v = ldv(hinitwv, j0 + jl, isf32) + ldv(hinitbv, j0 + jl, isf32);
        hst[bb][jl] = v;
        h0buf[(size_t)(b0 + bb) * HD + j0 + jl] = f2bf(v);
    }

    grid.sync();                       // h0 visible everywhere

    // ---- recurrence ----
    for (int t = 0; t < TS; ++t) {
        const u16* cur = (t & 1) ? h1buf : h0buf;
        u16*       nxt = (t & 1) ? h0buf : h1buf;

        f32x16 acc;
        #pragma unroll
        for (int i = 0; i < 16; ++i) acc[i] = 0.0f;
        float dacc = 0.0f;

        const u16* ap = cur + (size_t)(b0 + arow) * HD + khalf * 8;

        if (t > 0) {
            #pragma unroll 4
            for (int s = s0; s < s0 + 16; ++s) {
                bf16x8 a = *(const bf16x8*)(ap + s * 16);
                bf16x8 b = *(const bf16x8*)(&WB[(s * 64 + lane) * 8]);
                bf16x8 d = *(const bf16x8*)(&DEC[s * 16 + khalf * 8]);
                acc = __builtin_amdgcn_mfma_f32_32x32x16_bf16(a, b, acc, 0, 0, 0);
                #pragma unroll
                for (int i = 0; i < 8; ++i)
                    dacc += bf2f((u16)a[i]) * bf2f((u16)d[i]);   // decode of h_t -> out[t-1]
            }
        } else {
            #pragma unroll 4
            for (int s = s0; s < s0 + 16; ++s) {
                bf16x8 a = *(const bf16x8*)(ap + s * 16);
                bf16x8 b = *(const bf16x8*)(&WB[(s * 64 + lane) * 8]);
                acc = __builtin_amdgcn_mfma_f32_32x32x16_bf16(a, b, acc, 0, 0, 0);
            }
        }
        if (wave == 0) {               // enc tail: K=64 from x, zero-padded fgt columns
            bf16x8 af[4];
            if (isf32) {
                const float* xp = (const float*)xv + (size_t)(b0 + arow) * (TS * NI) + (size_t)t * NI + khalf * 8;
                #pragma unroll
                for (int s4 = 0; s4 < 4; ++s4) {
                    #pragma unroll
                    for (int i = 0; i < 8; ++i)
                        af[s4][i] = (short)f2bf(xp[s4 * 16 + i]);
                }
            } else {
                const u16* xp = (const u16*)xv + (size_t)(b0 + arow) * (TS * NI) + (size_t)t * NI + khalf * 8;
                #pragma unroll
                for (int s4 = 0; s4 < 4; ++s4)
                    af[s4] = *(const bf16x8*)(xp + s4 * 16);
            }
            #pragma unroll
            for (int s4 = 0; s4 < 4; ++s4) {
                bf16x8 b = *(const bf16x8*)(&WB[((64 + s4) * 64 + lane) * 8]);
                acc = __builtin_amdgcn_mfma_f32_32x32x16_bf16(af[s4], b, acc, 0, 0, 0);
            }
        }

        // spill partial C tiles (32x32: col=lane&31, row=(r&3)+8*(r>>2)+4*khalf)
        #pragma unroll
        for (int r = 0; r < 16; ++r) {
            int row = (r & 3) + 8 * (r >> 2) + 4 * khalf;
            redC[wave][row][lane & 31] = acc[r];
        }
        if (t > 0) {
            dacc += __shfl_xor(dacc, 32, 64);
            if (lane < 32) decred[wave][lane] = dacc;
        }
        __syncthreads();

        // elementwise update: cols 0..15 = pre_rec(+enc), cols 16..31 = pre_fgt
        for (int e = tid; e < 512; e += NT) {
            int bb = e >> 4, jl = e & 15;
            float pr = redC[0][bb][jl] + redC[1][bb][jl] + redC[2][bb][jl] + redC[3][bb][jl] + encbS[jl];
            float pf = redC[0][bb][jl + 16] + redC[1][bb][jl + 16] + redC[2][bb][jl + 16] + redC[3][bb][jl + 16];
            float fg = 1.0f / (1.0f + __expf(-pf));
            float hn = pr / (1.0f + fabsf(pr));
            float h  = hst[bb][jl];
            float hv = h + fg * (hn - h);
            hst[bb][jl] = hv;
            nxt[(size_t)(b0 + bb) * HD + j0 + jl] = f2bf(hv);
        }
        if (t > 0 && tid < 32) {
            float o = decred[0][tid] + decred[1][tid] + decred[2][tid] + decred[3][tid] + decbS;
            size_t oi = (size_t)(t - 1) * (BS * NO) + (size_t)(b0 + tid) * NO + g;
            if (isf32) ((float*)outv)[oi] = o; else ((u16*)outv)[oi] = f2bf(o);
        }

        grid.sync();
    }

    // ---- epilogue: out[511] = decode(h_512) (h_512 lives in h0buf), plus final hidden ----
    {
        const u16* cur = h0buf;
        float dacc = 0.0f;
        const u16* ap = cur + (size_t)(b0 + arow) * HD + khalf * 8;
        for (int s = s0; s < s0 + 16; ++s) {
            bf16x8 a = *(const bf16x8*)(ap + s * 16);
            bf16x8 d = *(const bf16x8*)(&DEC[s * 16 + khalf * 8]);
            #pragma unroll
            for (int i = 0; i < 8; ++i)
                dacc += bf2f((u16)a[i]) * bf2f((u16)d[i]);
        }
        dacc += __shfl_xor(dacc, 32, 64);
        if (lane < 32) decred[wave][lane] = dacc;
        __syncthreads();
        if (tid < 32) {
            float o = decred[0][tid] + decred[1][tid] + decred[2][tid] + decred[3][tid] + decbS;
            size_t oi = (size_t)511 * (BS * NO) + (size_t)(b0 + tid) * NO + g;
            if (isf32) ((float*)outv)[oi] = o; else ((u16*)outv)[oi] = f2bf(o);
        }
        for (int e = tid; e < 512; e += NT) {
            int bb = e >> 4, jl = e & 15;
            size_t oi = (size_t)TS * BS * NO + (size_t)(b0 + bb) * HD + j0 + jl;
            float v = hst[bb][jl];
            if (isf32) ((float*)outv)[oi] = v; else ((u16*)outv)[oi] = f2bf(v);
        }
    }
}

extern "C" void kernel_launch(void* const* d_in, const int* in_sizes, int n_in,
                              void* d_out, int out_size, void* d_ws, size_t ws_size,
                              hipStream_t stream) {
    (void)in_sizes; (void)n_in; (void)out_size; (void)ws_size;
    const void* xv       = d_in[0];
    const void* encwv    = d_in[1];
    const void* encbv    = d_in[2];
    const void* recwv    = d_in[3];
    const void* fgtwv    = d_in[4];
    const void* decwv    = d_in[5];
    const void* decbv    = d_in[6];
    const void* hinitwv  = d_in[7];
    const void* hinitbv  = d_in[8];
    void* outv = d_out;

    u16* h0buf = (u16*)d_ws;
    u16* h1buf = h0buf + (size_t)BS * HD;

    void* args[] = { (void*)&xv, (void*)&encwv, (void*)&encbv, (void*)&recwv,
                     (void*)&fgtwv, (void*)&decwv, (void*)&decbv,
                     (void*)&hinitwv, (void*)&hinitbv,
                     (void*)&outv, (void*)&h0buf, (void*)&h1buf };
    hipLaunchCooperativeKernel((void*)arnn_persist, dim3(NWG), dim3(NT), args, 0, stream);
}

// Round 3
// 10197.430 us; speedup vs baseline: 1.7292x; 1.7292x over previous
//
#include <hip/hip_runtime.h>

typedef unsigned short u16;

#define NWG 256
#define NT  256
#define TS  512
#define HD  1024
#define BS  128
#define NI  64
#define NO  64

typedef __attribute__((ext_vector_type(8)))  short bf16x8;
typedef __attribute__((ext_vector_type(16))) float f32x16;

__device__ __forceinline__ float bf2f(u16 u) {
    union { unsigned int i; float f; } v; v.i = ((unsigned int)u) << 16; return v.f;
}
__device__ __forceinline__ u16 f2bf(float f) {
    union { float fl; unsigned int i; } v; v.fl = f;
    unsigned int x = v.i;
    return (u16)((x + 0x7fffu + ((x >> 16) & 1u)) >> 16);  // RNE, finite inputs
}
__device__ __forceinline__ float ldv(const void* p, size_t i, bool isf32) {
    return isf32 ? ((const float*)p)[i] : bf2f(((const u16*)p)[i]);
}

// Spin until all 64 flags of this quarter reach `target`, then agent-acquire.
// flag[g] = v  <=>  "WG g has published h_{v-1} AND retired its reads of h_{v-2}".
// Relaxed agent loads in the spin (no per-iter L2 invalidate); ONE acquire
// fence on exit makes the published hidden data visible.
__device__ __forceinline__ void wait_quarter(const unsigned* qflags, int lane, unsigned target) {
    for (;;) {
        unsigned f = __hip_atomic_load(&qflags[lane], __ATOMIC_RELAXED, __HIP_MEMORY_SCOPE_AGENT);
        if (__all((int)(f >= target))) break;
        __builtin_amdgcn_s_sleep(1);
    }
    __builtin_amdgcn_fence(__ATOMIC_ACQUIRE, "agent");
}

// LDS ~91KB -> 1 WG/CU; grid=256 = CU count; cooperative launch guarantees
// co-residency so the flag spin cannot deadlock. cg::sync() is NOT used --
// quarters only ever exchange data among their own 64 WGs, so a 64-flag
// producer/consumer sync replaces the (measured ~35us/step) grid barrier.
__global__ __launch_bounds__(NT)
void arnn_persist(const void* __restrict__ xv,
                  const void* __restrict__ encwv,
                  const void* __restrict__ encbv,
                  const void* __restrict__ recwv,
                  const void* __restrict__ fgtwv,
                  const void* __restrict__ decwv,
                  const void* __restrict__ decbv,
                  const void* __restrict__ hinitwv,
                  const void* __restrict__ hinitbv,
                  void* __restrict__ outv,
                  u16* __restrict__ h0buf,
                  u16* __restrict__ h1buf,
                  unsigned* __restrict__ flags)
{
    // B-fragments pre-swizzled in MFMA lane order: WB[s][lane][8] = W'[lane&31][s*16 + 8*(lane>>5) + i]
    // rows n<16: rec_w[j0+n][k] (k<1024) then enc_w[j0+n][k-1024] (64 cols); rows n>=16: fgt_w, then zeros.
    __shared__ short WB[68 * 64 * 8];      // 69632 B
    __shared__ short DEC[HD];              // 2048 B: dec_w[g][:]
    __shared__ float redC[4][32][33];      // 16896 B (pad 33 breaks bank conflicts)
    __shared__ float hst[32][16];          // fp32 master copy of owned hidden slice
    __shared__ float encbS[16];
    __shared__ float decred[4][32];
    __shared__ float decbS;
    __shared__ int   s_f32;

    const int tid  = threadIdx.x;
    const int wg   = blockIdx.x;
    const int q    = wg >> 6;          // batch quarter 0..3
    const int g    = wg & 63;          // column group 0..63 (also the dec output column)
    const int b0   = q * 32;
    const int j0   = g * 16;
    const int wave = tid >> 6;
    const int lane = tid & 63;
    const int arow = lane & 31;        // A-fragment row (batch-local)
    const int khalf = lane >> 5;       // k half within 16-wide MFMA K
    const int s0   = wave * 16;        // K split: wave w handles k-steps [16w, 16w+16)

    const unsigned* qflags = flags + q * 64;
    unsigned* myflag = flags + q * 64 + g;

    // ---- runtime dtype detection on rec_w raw bits ----
    if (tid == 0) s_f32 = 0;
    __syncthreads();
    {
        float v = bf2f(((const u16*)recwv)[tid]);
        if (!(v >= -1.0f && v <= 1.0f)) s_f32 = 1;   // fp32 mantissa halves -> huge/NaN bf16
    }
    __syncthreads();
    const bool isf32 = (s_f32 != 0);

    // ---- init: stage weights into LDS (as bf16) in fragment order ----
    for (int slot = tid; slot < 68 * 64; slot += NT) {
        int s = slot >> 6, l = slot & 63;
        int n = l & 31;
        int kb = s * 16 + 8 * (l >> 5);
        short v[8];
        if (n < 16) {
            int j = j0 + n;
            #pragma unroll
            for (int i = 0; i < 8; ++i) {
                int k = kb + i;
                float w = (k < HD) ? ldv(recwv, (size_t)j * HD + k, isf32)
                                   : ldv(encwv, (size_t)j * NI + (k - HD), isf32);
                v[i] = (short)f2bf(w);
            }
        } else {
            int j = j0 + n - 16;
            #pragma unroll
            for (int i = 0; i < 8; ++i) {
                int k = kb + i;
                v[i] = (k < HD) ? (short)f2bf(ldv(fgtwv, (size_t)j * HD + k, isf32)) : (short)0;
            }
        }
        #pragma unroll
        for (int i = 0; i < 8; ++i) WB[slot * 8 + i] = v[i];
    }
    for (int k = tid; k < HD; k += NT) DEC[k] = (short)f2bf(ldv(decwv, (size_t)g * HD + k, isf32));
    if (tid < 16) encbS[tid] = ldv(encbv, j0 + tid, isf32);
    if (tid == 0) decbS = ldv(decbv, g, isf32);
    // h0 = hinit_w[:,0] + hinit_b (same for every batch row); fp32 local, bf16 global
    for (int e = tid; e < 512; e += NT) {
        int bb = e >> 4, jl = e & 15;
        float v = ldv(hinitwv, j0 + jl, isf32) + ldv(hinitbv, j0 + jl, isf32);
        hst[bb][jl] = v;
        h0buf[(size_t)(b0 + bb) * HD + j0 + jl] = f2bf(v);
    }

    __syncthreads();                   // all waves' h0 stores drained to L2
    if (tid == 0)                      // release: L2 writeback, then publish
        __hip_atomic_store(myflag, 1u, __ATOMIC_RELEASE, __HIP_MEMORY_SCOPE_AGENT);

    // ---- recurrence ----
    // WAR safety: at step t we overwrite buf[(t+1)&1] (= h_{t-1}'s storage).
    // wait(t+1) guarantees every peer retired its h_{t-1} reads (flag t+1 is
    // only set after a peer's step-t... see flag definition: flag >= t+1 means
    // reads of h_{t-1} are done), so the overwrite cannot race a reader.
    for (int t = 0; t < TS; ++t) {
        wait_quarter(qflags, lane, (unsigned)(t + 1));   // h_t published by all peers

        const u16* cur = (t & 1) ? h1buf : h0buf;
        u16*       nxt = (t & 1) ? h0buf : h1buf;

        f32x16 acc;
        #pragma unroll
        for (int i = 0; i < 16; ++i) acc[i] = 0.0f;
        float dacc = 0.0f;

        const u16* ap = cur + (size_t)(b0 + arow) * HD + khalf * 8;

        if (t > 0) {
            #pragma unroll 4
            for (int s = s0; s < s0 + 16; ++s) {
                bf16x8 a = *(const bf16x8*)(ap + s * 16);
                bf16x8 b = *(const bf16x8*)(&WB[(s * 64 + lane) * 8]);
                bf16x8 d = *(const bf16x8*)(&DEC[s * 16 + khalf * 8]);
                acc = __builtin_amdgcn_mfma_f32_32x32x16_bf16(a, b, acc, 0, 0, 0);
                #pragma unroll
                for (int i = 0; i < 8; ++i)
                    dacc += bf2f((u16)a[i]) * bf2f((u16)d[i]);   // decode of h_t -> out[t-1]
            }
        } else {
            #pragma unroll 4
            for (int s = s0; s < s0 + 16; ++s) {
                bf16x8 a = *(const bf16x8*)(ap + s * 16);
                bf16x8 b = *(const bf16x8*)(&WB[(s * 64 + lane) * 8]);
                acc = __builtin_amdgcn_mfma_f32_32x32x16_bf16(a, b, acc, 0, 0, 0);
            }
        }
        if (wave == 0) {               // enc tail: K=64 from x, zero-padded fgt columns
            bf16x8 af[4];
            if (isf32) {
                const float* xp = (const float*)xv + (size_t)(b0 + arow) * (TS * NI) + (size_t)t * NI + khalf * 8;
                #pragma unroll
                for (int s4 = 0; s4 < 4; ++s4) {
                    #pragma unroll
                    for (int i = 0; i < 8; ++i)
                        af[s4][i] = (short)f2bf(xp[s4 * 16 + i]);
                }
            } else {
                const u16* xp = (const u16*)xv + (size_t)(b0 + arow) * (TS * NI) + (size_t)t * NI + khalf * 8;
                #pragma unroll
                for (int s4 = 0; s4 < 4; ++s4)
                    af[s4] = *(const bf16x8*)(xp + s4 * 16);
            }
            #pragma unroll
            for (int s4 = 0; s4 < 4; ++s4) {
                bf16x8 b = *(const bf16x8*)(&WB[((64 + s4) * 64 + lane) * 8]);
                acc = __builtin_amdgcn_mfma_f32_32x32x16_bf16(af[s4], b, acc, 0, 0, 0);
            }
        }

        // spill partial C tiles (32x32: col=lane&31, row=(r&3)+8*(r>>2)+4*khalf)
        #pragma unroll
        for (int r = 0; r < 16; ++r) {
            int row = (r & 3) + 8 * (r >> 2) + 4 * khalf;
            redC[wave][row][lane & 31] = acc[r];
        }
        if (t > 0) {
            dacc += __shfl_xor(dacc, 32, 64);
            if (lane < 32) decred[wave][lane] = dacc;
        }
        __syncthreads();

        // elementwise update: cols 0..15 = pre_rec(+enc), cols 16..31 = pre_fgt
        for (int e = tid; e < 512; e += NT) {
            int bb = e >> 4, jl = e & 15;
            float pr = redC[0][bb][jl] + redC[1][bb][jl] + redC[2][bb][jl] + redC[3][bb][jl] + encbS[jl];
            float pf = redC[0][bb][jl + 16] + redC[1][bb][jl + 16] + redC[2][bb][jl + 16] + redC[3][bb][jl + 16];
            float fg = 1.0f / (1.0f + __expf(-pf));
            float hn = pr / (1.0f + fabsf(pr));
            float h  = hst[bb][jl];
            float hv = h + fg * (hn - h);
            hst[bb][jl] = hv;
            nxt[(size_t)(b0 + bb) * HD + j0 + jl] = f2bf(hv);
        }
        if (t > 0 && tid < 32) {
            float o = decred[0][tid] + decred[1][tid] + decred[2][tid] + decred[3][tid] + decbS;
            size_t oi = (size_t)(t - 1) * (BS * NO) + (size_t)(b0 + tid) * NO + g;
            if (isf32) ((float*)outv)[oi] = o; else ((u16*)outv)[oi] = f2bf(o);
        }

        __syncthreads();               // all waves' h_{t+1} stores + redC reads retired
        if (tid == 0)                  // release: L2 writeback, publish h_{t+1}
            __hip_atomic_store(myflag, (unsigned)(t + 2), __ATOMIC_RELEASE, __HIP_MEMORY_SCOPE_AGENT);
    }

    // ---- epilogue: out[511] = decode(h_512) (h_512 lives in h0buf), plus final hidden ----
    wait_quarter(qflags, lane, (unsigned)(TS + 1));      // h_512 published by all peers
    {
        const u16* cur = h0buf;
        float dacc = 0.0f;
        const u16* ap = cur + (size_t)(b0 + arow) * HD + khalf * 8;
        for (int s = s0; s < s0 + 16; ++s) {
            bf16x8 a = *(const bf16x8*)(ap + s * 16);
            bf16x8 d = *(const bf16x8*)(&DEC[s * 16 + khalf * 8]);
            #pragma unroll
            for (int i = 0; i < 8; ++i)
                dacc += bf2f((u16)a[i]) * bf2f((u16)d[i]);
        }
        dacc += __shfl_xor(dacc, 32, 64);
        if (lane < 32) decred[wave][lane] = dacc;
        __syncthreads();
        if (tid < 32) {
            float o = decred[0][tid] + decred[1][tid] + decred[2][tid] + decred[3][tid] + decbS;
            size_t oi = (size_t)511 * (BS * NO) + (size_t)(b0 + tid) * NO + g;
            if (isf32) ((float*)outv)[oi] = o; else ((u16*)outv)[oi] = f2bf(o);
        }
        for (int e = tid; e < 512; e += NT) {
            int bb = e >> 4, jl = e & 15;
            size_t oi = (size_t)TS * BS * NO + (size_t)(b0 + bb) * HD + j0 + jl;
            float v = hst[bb][jl];
            if (isf32) ((float*)outv)[oi] = v; else ((u16*)outv)[oi] = f2bf(v);
        }
    }
}

extern "C" void kernel_launch(void* const* d_in, const int* in_sizes, int n_in,
                              void* d_out, int out_size, void* d_ws, size_t ws_size,
                              hipStream_t stream) {
    (void)in_sizes; (void)n_in; (void)out_size; (void)ws_size;
    const void* xv       = d_in[0];
    const void* encwv    = d_in[1];
    const void* encbv    = d_in[2];
    const void* recwv    = d_in[3];
    const void* fgtwv    = d_in[4];
    const void* decwv    = d_in[5];
    const void* decbv    = d_in[6];
    const void* hinitwv  = d_in[7];
    const void* hinitbv  = d_in[8];
    void* outv = d_out;

    unsigned* flags = (unsigned*)d_ws;                  // 4 quarters x 64 flags
    u16* h0buf = (u16*)((char*)d_ws + 4096);
    u16* h1buf = h0buf + (size_t)BS * HD;

    hipMemsetAsync(d_ws, 0, 4096, stream);              // flags start at 0 every launch

    void* args[] = { (void*)&xv, (void*)&encwv, (void*)&encbv, (void*)&recwv,
                     (void*)&fgtwv, (void*)&decwv, (void*)&decbv,
                     (void*)&hinitwv, (void*)&hinitbv,
                     (void*)&outv, (void*)&h0buf, (void*)&h1buf, (void*)&flags };
    hipLaunchCooperativeKernel((void*)arnn_persist, dim3(NWG), dim3(NT), args, 0, stream);
}

// Round 4
// 7249.060 us; speedup vs baseline: 2.4325x; 1.4067x over previous
//
#include <hip/hip_runtime.h>

typedef unsigned short u16;

#define NWG 256
#define NT  256
#define TS  512
#define HD  1024
#define BS  128
#define NI  64
#define NO  64
#define XR  16      // batch rows per XCD
#define CC  32      // hidden cols per CU

typedef __attribute__((ext_vector_type(8))) short bf16x8;
typedef __attribute__((ext_vector_type(4))) float f32x4;

__device__ __forceinline__ float bf2f(u16 u) {
    union { unsigned int i; float f; } v; v.i = ((unsigned int)u) << 16; return v.f;
}
__device__ __forceinline__ u16 f2bf(float f) {
    union { float fl; unsigned int i; } v; v.fl = f;
    unsigned int x = v.i;
    return (u16)((x + 0x7fffu + ((x >> 16) & 1u)) >> 16);  // RNE, finite inputs
}
__device__ __forceinline__ float ldv(const void* p, size_t i, bool isf32) {
    return isf32 ? ((const float*)p)[i] : bf2f(((const u16*)p)[i]);
}

// L2-executed atomic add returning old value (sc0 = return-old; NO sc1 -> stays
// in the XCD-local L2, which is the coherence point for all flags/data here).
__device__ __forceinline__ unsigned l2_atomic_add(unsigned* p, unsigned v) {
    unsigned old;
    asm volatile("global_atomic_add %0, %1, %2, off sc0\n\t"
                 "s_waitcnt vmcnt(0)"
                 : "=&v"(old) : "v"(p), "v"(v) : "memory");
    return old;
}

// Spin until all 32 per-CU flags of this XCD reach target. Flags are read via
// L2-executed atomic add(0) (bypasses L1; no compiler peephole can turn the asm
// into a cacheable load). 64B stride between flags avoids same-line contention.
__device__ __forceinline__ void wait_flags(unsigned* qbase, int lane, unsigned target) {
    unsigned* p = qbase + (lane & 31) * 16;
    for (;;) {
        unsigned f = l2_atomic_add(p, 0u);
        if (__all((int)(f >= target))) break;
        __builtin_amdgcn_s_sleep(2);
    }
}

// 8 A-fragments (one K-quarter: 8 k-steps x 16B) loaded with sc0 (L1 bypass ->
// read through the XCD-local L2, where peer CUs' write-through stores live).
__device__ __forceinline__ void load_a_frags(const u16* ap, bf16x8* a) {
    asm volatile(
        "global_load_dwordx4 %0, %8, off sc0\n\t"
        "global_load_dwordx4 %1, %8, off offset:64 sc0\n\t"
        "global_load_dwordx4 %2, %8, off offset:128 sc0\n\t"
        "global_load_dwordx4 %3, %8, off offset:192 sc0\n\t"
        "global_load_dwordx4 %4, %8, off offset:256 sc0\n\t"
        "global_load_dwordx4 %5, %8, off offset:320 sc0\n\t"
        "global_load_dwordx4 %6, %8, off offset:384 sc0\n\t"
        "global_load_dwordx4 %7, %8, off offset:448 sc0\n\t"
        "s_waitcnt vmcnt(0)"
        : "=&v"(a[0]), "=&v"(a[1]), "=&v"(a[2]), "=&v"(a[3]),
          "=&v"(a[4]), "=&v"(a[5]), "=&v"(a[6]), "=&v"(a[7])
        : "v"(ap) : "memory");
}

// LDS ~154KB -> exactly 1 WG/CU; cooperative launch => all 256 WGs co-resident
// => every XCD hosts exactly 32 WGs (1 per CU). WGs self-identify their XCD via
// s_getreg(HW_REG_XCC_ID) and claim a per-XCD ticket, so all flag/hidden
// traffic is XCD-local (single shared L2; no wbl2/inv/L3 in the hot loop).
// Failure mode if placement assumptions break: deadlock (loud), not corruption.
__global__ __launch_bounds__(NT)
void arnn_xcd(const void* __restrict__ xv,
              const void* __restrict__ encwv,
              const void* __restrict__ encbv,
              const void* __restrict__ recwv,
              const void* __restrict__ fgtwv,
              const void* __restrict__ decwv,
              const void* __restrict__ decbv,
              const void* __restrict__ hinitwv,
              const void* __restrict__ hinitbv,
              void* __restrict__ outv,
              u16* __restrict__ h0buf,
              u16* __restrict__ h1buf,
              unsigned* __restrict__ tickets,
              unsigned* __restrict__ flags)
{
    // WB: 4 n-tiles of 16 cols in MFMA B-frag lane order.
    // tile0: rec cols j0..j0+15, 34 k-steps (32 rec K=1024 + 2 enc K=64)
    // tile1: rec cols j0+16..j0+31, 34 k-steps
    // tile2/3: fgt cols, 32 k-steps. Entry: WB[(tb+ks)*64 + lane][8].
    __shared__ short WB[132 * 64 * 8];        // 135168 B
    __shared__ float redC[4 * 5 * 16 * 16];   // 20480 B: [kq][tile(4=dec)][row][col]
    __shared__ float hst[XR * CC];            // fp32 master hidden slice
    __shared__ float encbS[CC];
    __shared__ float decbLS[16];
    __shared__ unsigned s_xcd, s_slot;
    __shared__ int s_f32;

    const int tid  = threadIdx.x;
    const int wave = tid >> 6;
    const int lane = tid & 63;
    const int m    = lane & 15;      // C row / A row (batch-local)
    const int quad = lane >> 4;      // k-subblock within K=32

    // ---- identify XCD, claim per-XCD CU slot ----
    if (tid == 0) {
        unsigned xcc;
        asm volatile("s_getreg_b32 %0, hwreg(HW_REG_XCC_ID, 0, 4)" : "=s"(xcc));
        xcc &= 7u;
        unsigned slot = l2_atomic_add(tickets + xcc * 16, 1u);
        s_xcd = xcc;
        s_slot = slot & 31u;
        s_f32 = 0;
    }
    __syncthreads();
    { // runtime dtype detection on rec_w raw bits (round-1 post-mortem)
        float v = bf2f(((const u16*)recwv)[tid]);
        if (!(v >= -1.0f && v <= 1.0f)) s_f32 = 1;
    }
    __syncthreads();
    const bool isf32 = (s_f32 != 0);
    const int xcd  = (int)s_xcd;
    const int slot = (int)s_slot;
    const int b0   = xcd * XR;       // this XCD's batch rows
    const int j0   = slot * CC;      // this CU's hidden cols
    const int dt   = slot & 3;       // dec tile: out cols 16dt..16dt+15
    unsigned* qbase  = flags + xcd * 32 * 16;
    unsigned* myflag = qbase + slot * 16;

    // ---- stage weights into LDS in B-frag order ----
    for (int idx = tid; idx < 132 * 64; idx += NT) {
        int ksg = idx >> 6, l = idx & 63, n = l & 15, q = l >> 4;
        int tile, ksl;
        if (ksg < 34)       { tile = 0; ksl = ksg; }
        else if (ksg < 68)  { tile = 1; ksl = ksg - 34; }
        else if (ksg < 100) { tile = 2; ksl = ksg - 68; }
        else                { tile = 3; ksl = ksg - 100; }
        int j = j0 + ((tile & 1) << 4) + n;
        bf16x8 v;
        if (!isf32) {
            const u16* src;
            if (tile < 2) src = (ksl < 32) ? (const u16*)recwv + (size_t)j * HD + ksl * 32 + q * 8
                                           : (const u16*)encwv + (size_t)j * NI + (ksl - 32) * 32 + q * 8;
            else          src = (const u16*)fgtwv + (size_t)j * HD + ksl * 32 + q * 8;
            v = *(const bf16x8*)src;
        } else {
            const float* src;
            if (tile < 2) src = (ksl < 32) ? (const float*)recwv + (size_t)j * HD + ksl * 32 + q * 8
                                           : (const float*)encwv + (size_t)j * NI + (ksl - 32) * 32 + q * 8;
            else          src = (const float*)fgtwv + (size_t)j * HD + ksl * 32 + q * 8;
            #pragma unroll
            for (int i = 0; i < 8; ++i) v[i] = (short)f2bf(src[i]);
        }
        *(bf16x8*)&WB[idx * 8] = v;
    }

    // ---- dec B-frags for this wave's K-quarter, kept in VGPRs (32) ----
    bf16x8 dfr[8];
    {
        int o = 16 * dt + m;         // out column
        #pragma unroll
        for (int ks = 0; ks < 8; ++ks) {
            int kb = wave * 256 + ks * 32 + quad * 8;
            if (!isf32) dfr[ks] = *(const bf16x8*)((const u16*)decwv + (size_t)o * HD + kb);
            else {
                const float* src = (const float*)decwv + (size_t)o * HD + kb;
                #pragma unroll
                for (int i = 0; i < 8; ++i) dfr[ks][i] = (short)f2bf(src[i]);
            }
        }
    }
    if (tid < CC) encbS[tid] = ldv(encbv, j0 + tid, isf32);
    if (tid < 16) decbLS[tid] = ldv(decbv, 16 * dt + tid, isf32);
    // h0 = hinit_w[:,0] + hinit_b (same for all batch rows)
    for (int e = tid; e < XR * CC; e += NT) {
        int r = e >> 5, c = e & 31;
        float v = ldv(hinitwv, j0 + c, isf32) + ldv(hinitbv, j0 + c, isf32);
        hst[e] = v;
        h0buf[(size_t)(b0 + r) * HD + j0 + c] = f2bf(v);
    }
    __syncthreads();                         // drains h0 stores to L2 (vmcnt(0))
    if (tid == 0) l2_atomic_add(myflag, 1u); // publish h0: flag = 1

    // ---- recurrence ----
    // flag = v <=> "published h_{v-1} AND retired reads of h_{v-2}", so the
    // ping-pong overwrite of h_{t-1}'s storage at step t is WAR-safe once all
    // 32 peer flags reach t+1.
    for (int t = 0; t < TS; ++t) {
        wait_flags(qbase, lane, (unsigned)(t + 1));

        const u16* cur = (t & 1) ? h1buf : h0buf;
        u16*       nxt = (t & 1) ? h0buf : h1buf;

        bf16x8 a[8];
        load_a_frags(cur + (size_t)(b0 + m) * HD + wave * 256 + quad * 8, a);

        bf16x8 xf;
        if (wave < 2) {                       // enc tail A-frag from x (read-only)
            size_t xb = (size_t)(b0 + m) * (TS * NI) + (size_t)t * NI + wave * 32 + quad * 8;
            if (!isf32) xf = *(const bf16x8*)((const u16*)xv + xb);
            else {
                const float* xp = (const float*)xv + xb;
                #pragma unroll
                for (int i = 0; i < 8; ++i) xf[i] = (short)f2bf(xp[i]);
            }
        }

        f32x4 acc[5];
        #pragma unroll
        for (int tt = 0; tt < 5; ++tt) acc[tt] = (f32x4){0.f, 0.f, 0.f, 0.f};

        #pragma unroll
        for (int ks = 0; ks < 8; ++ks) {
            int kb = wave * 8 + ks;
            bf16x8 bf0 = *(const bf16x8*)&WB[((0   + kb) * 64 + lane) * 8];
            bf16x8 bf1 = *(const bf16x8*)&WB[((34  + kb) * 64 + lane) * 8];
            bf16x8 bf2 = *(const bf16x8*)&WB[((68  + kb) * 64 + lane) * 8];
            bf16x8 bf3 = *(const bf16x8*)&WB[((100 + kb) * 64 + lane) * 8];
            acc[0] = __builtin_amdgcn_mfma_f32_16x16x32_bf16(a[ks], bf0, acc[0], 0, 0, 0);
            acc[1] = __builtin_amdgcn_mfma_f32_16x16x32_bf16(a[ks], bf1, acc[1], 0, 0, 0);
            acc[2] = __builtin_amdgcn_mfma_f32_16x16x32_bf16(a[ks], bf2, acc[2], 0, 0, 0);
            acc[3] = __builtin_amdgcn_mfma_f32_16x16x32_bf16(a[ks], bf3, acc[3], 0, 0, 0);
            acc[4] = __builtin_amdgcn_mfma_f32_16x16x32_bf16(a[ks], dfr[ks], acc[4], 0, 0, 0);
        }
        if (wave < 2) {                       // enc tail (rec tiles only)
            bf16x8 e0 = *(const bf16x8*)&WB[((32 + wave) * 64 + lane) * 8];
            bf16x8 e1 = *(const bf16x8*)&WB[((34 + 32 + wave) * 64 + lane) * 8];
            acc[0] = __builtin_amdgcn_mfma_f32_16x16x32_bf16(xf, e0, acc[0], 0, 0, 0);
            acc[1] = __builtin_amdgcn_mfma_f32_16x16x32_bf16(xf, e1, acc[1], 0, 0, 0);
        }

        // C-layout 16x16: col = lane&15, row = quad*4 + reg
        #pragma unroll
        for (int tt = 0; tt < 5; ++tt) {
            #pragma unroll
            for (int r = 0; r < 4; ++r)
                redC[((wave * 5 + tt) * 16 + quad * 4 + r) * 16 + m] = acc[tt][r];
        }
        __syncthreads();

        // cross-wave K-reduction + elementwise update + h store
        for (int e = tid; e < XR * CC; e += NT) {
            int r = e >> 5, c = e & 31, tl = c >> 4, col = c & 15;
            float pr = encbS[c], pf = 0.f;
            #pragma unroll
            for (int kq = 0; kq < 4; ++kq) {
                pr += redC[((kq * 5 + tl) * 16 + r) * 16 + col];
                pf += redC[((kq * 5 + 2 + tl) * 16 + r) * 16 + col];
            }
            float fg = 1.0f / (1.0f + __expf(-pf));
            float hn = pr / (1.0f + fabsf(pr));
            float h  = hst[e];
            float hv = h + fg * (hn - h);
            hst[e] = hv;
            nxt[(size_t)(b0 + r) * HD + j0 + c] = f2bf(hv);
        }
        // decode h_t -> out[t-1] (dec tiles replicated 8x; slots 0..3 write)
        if (slot < 4 && t > 0) {
            int r = tid >> 4, col = tid & 15;
            float o = decbLS[col];
            #pragma unroll
            for (int kq = 0; kq < 4; ++kq)
                o += redC[((kq * 5 + 4) * 16 + r) * 16 + col];
            size_t oi = (size_t)(t - 1) * (BS * NO) + (size_t)(b0 + r) * NO + 16 * dt + col;
            if (isf32) ((float*)outv)[oi] = o; else ((u16*)outv)[oi] = f2bf(o);
        }
        __syncthreads();                          // drains h stores (vmcnt(0))
        if (tid == 0) l2_atomic_add(myflag, 1u);  // publish h_{t+1}: flag = t+2
    }

    // ---- epilogue: out[511] = decode(h_512); final hidden ----
    wait_flags(qbase, lane, (unsigned)(TS + 1));
    {
        bf16x8 a[8];
        load_a_frags(h0buf + (size_t)(b0 + m) * HD + wave * 256 + quad * 8, a);
        f32x4 ac = (f32x4){0.f, 0.f, 0.f, 0.f};
        #pragma unroll
        for (int ks = 0; ks < 8; ++ks)
            ac = __builtin_amdgcn_mfma_f32_16x16x32_bf16(a[ks], dfr[ks], ac, 0, 0, 0);
        #pragma unroll
        for (int r = 0; r < 4; ++r)
            redC[((wave * 5 + 4) * 16 + quad * 4 + r) * 16 + m] = ac[r];
        __syncthreads();
        if (slot < 4) {
            int r = tid >> 4, col = tid & 15;
            float o = decbLS[col];
            #pragma unroll
            for (int kq = 0; kq < 4; ++kq)
                o += redC[((kq * 5 + 4) * 16 + r) * 16 + col];
            size_t oi = (size_t)511 * (BS * NO) + (size_t)(b0 + r) * NO + 16 * dt + col;
            if (isf32) ((float*)outv)[oi] = o; else ((u16*)outv)[oi] = f2bf(o);
        }
        for (int e = tid; e < XR * CC; e += NT) {
            int r = e >> 5, c = e & 31;
            size_t oi = (size_t)TS * BS * NO + (size_t)(b0 + r) * HD + j0 + c;
            float v = hst[e];
            if (isf32) ((float*)outv)[oi] = v; else ((u16*)outv)[oi] = f2bf(v);
        }
    }
}

extern "C" void kernel_launch(void* const* d_in, const int* in_sizes, int n_in,
                              void* d_out, int out_size, void* d_ws, size_t ws_size,
                              hipStream_t stream) {
    (void)in_sizes; (void)n_in; (void)out_size; (void)ws_size;
    const void* xv       = d_in[0];
    const void* encwv    = d_in[1];
    const void* encbv    = d_in[2];
    const void* recwv    = d_in[3];
    const void* fgtwv    = d_in[4];
    const void* decwv    = d_in[5];
    const void* decbv    = d_in[6];
    const void* hinitwv  = d_in[7];
    const void* hinitbv  = d_in[8];
    void* outv = d_out;

    unsigned* tickets = (unsigned*)d_ws;                          // 8 x 64B-stride
    unsigned* flags   = (unsigned*)((char*)d_ws + 1024);          // 256 x 64B-stride
    u16* h0buf = (u16*)((char*)d_ws + 32768);
    u16* h1buf = h0buf + (size_t)BS * HD;

    hipMemsetAsync(d_ws, 0, 18432, stream);   // zero tickets + flags each launch

    void* args[] = { (void*)&xv, (void*)&encwv, (void*)&encbv, (void*)&recwv,
                     (void*)&fgtwv, (void*)&decwv, (void*)&decbv,
                     (void*)&hinitwv, (void*)&hinitbv,
                     (void*)&outv, (void*)&h0buf, (void*)&h1buf,
                     (void*)&tickets, (void*)&flags };
    hipLaunchCooperativeKernel((void*)arnn_xcd, dim3(NWG), dim3(NT), args, 0, stream);
}